// Round 9
// baseline (294.047 us; speedup 1.0000x reference)
//
#include <hip/hip_runtime.h>
#include <stdint.h>

#define IN_F   11008
#define OUT_F  4096
#define TOPK_K 5504
#define NCACHE 64
#define MASK_WORDS 344   // 11008 / 32
#define NTHR   512
#define NCHUNK 22        // ceil(11008 / 512)
#define ROWS_PER_BLOCK 16
#define NWORK  (OUT_F / ROWS_PER_BLOCK)   // 256 worker blocks, 1 per CU
#define NBLK   (1 + NWORK)                // 257

// ws layout (bytes):
//   [0    , 1376) : topk mask bits (344 u32)
//   [1472 , 1476) : packed score u32, atomicMax of (inter<<6)|(63-row)
//   [1476 , 1480) : mask-ready flag (release by block 0)
//   [1480 , 1484) : recall-done counter
// (score/flag/done zeroed by hipMemsetAsync before launch)
//
// MEASUREMENT ROUND: k_all is launched TWICE. Run 2 is idempotent (same mask
// recomputed; flag already 1 -> workers skip prefetch+wait; done 64->128 with
// spin at <64; out rewritten with identical values). dur_us delta vs R8
// isolates T(GEMV | warm L3, no sync exposure).

__device__ __forceinline__ unsigned absbits(float v) {
    return __float_as_uint(v) & 0x7fffffffu;
}

__global__ __launch_bounds__(NTHR, 4) void k_all(const float* __restrict__ x,
                                                 const float* __restrict__ W,
                                                 const float* __restrict__ bias,
                                                 const int* __restrict__ cached,
                                                 float* __restrict__ out,
                                                 unsigned* __restrict__ maskbits_g,
                                                 unsigned* __restrict__ score_g,
                                                 unsigned* __restrict__ flag_g,
                                                 unsigned* __restrict__ done_g) {
    __shared__ unsigned hist[8][256];    // select: per-wave private hists (8KB)
    __shared__ unsigned csum[256];
    __shared__ unsigned sh_T, sh_rem, sh_totEq;
    __shared__ unsigned waveEq[NCHUNK][8];
    __shared__ unsigned waveEqPre[NCHUNK][8];
    __shared__ unsigned rowbits[MASK_WORDS];   // recall
    __shared__ unsigned wsum[8];
    __shared__ __align__(16) float xs[IN_F];   // gemv (44KB); select reuses as x stage

    const int tid  = threadIdx.x;
    const int wv   = tid >> 6;
    const int lane = tid & 63;
    const int bid  = blockIdx.x;

    // ===================== block 0: radix-select =====================
    if (bid == 0) {
        // batched x ingest: 6 independent float4 loads -> LDS -> strided re-read
        {
            float4* xs4w = (float4*)xs;
#pragma unroll
            for (int k = 0; k < 6; ++k) {
                int j = k * NTHR + tid;
                if (j < IN_F / 4) xs4w[j] = ((const float4*)x)[j];
            }
        }
        __syncthreads();

        const int nk = (tid < 256) ? NCHUNK : NCHUNK - 1;   // 11008 = 21*512 + 256

        unsigned key[NCHUNK];
#pragma unroll
        for (int c = 0; c < NCHUNK; ++c) {
            key[c] = 0u;
            if (c < nk) key[c] = absbits(xs[c * NTHR + tid]);
        }
        __syncthreads();

        unsigned prefix = 0, maskHi = 0, remaining = TOPK_K;

        for (int pass = 3; pass >= 0; --pass) {
            const int sh = pass * 8;
            for (int b = tid; b < 8 * 256; b += NTHR) ((unsigned*)hist)[b] = 0;
            __syncthreads();
#pragma unroll
            for (int c = 0; c < NCHUNK; ++c) {
                if (c < nk && (key[c] & maskHi) == prefix)
                    atomicAdd(&hist[wv][(key[c] >> sh) & 255], 1u);
            }
            __syncthreads();
            if (tid < 256) {          // merge 8 hists, conflict-free
                unsigned s = 0;
#pragma unroll
                for (int w = 0; w < 8; ++w) s += hist[w][tid];
                csum[tid] = s;
            }
            __syncthreads();
            if (wv == 0) {
                // lane l owns buckets [4l,4l+4); inclusive suffix-scan across lanes
                unsigned c0 = csum[4 * lane + 0], c1 = csum[4 * lane + 1];
                unsigned c2 = csum[4 * lane + 2], c3 = csum[4 * lane + 3];
                unsigned S = c0 + c1 + c2 + c3;
#pragma unroll
                for (int off = 1; off < 64; off <<= 1) {
                    unsigned v = __shfl_down(S, off, 64);
                    if (lane + off < 64) S += v;
                }
                unsigned Sn = __shfl_down(S, 1, 64);
                if (lane == 63) Sn = 0;
                unsigned t3 = Sn + c3;
                unsigned t2 = t3 + c2;
                unsigned t1 = t2 + c1;
                unsigned t0 = t1 + c0;
                unsigned rem = remaining;
                if (t3 >= rem && Sn < rem) { sh_T = prefix | ((unsigned)(4 * lane + 3) << sh); sh_rem = rem - Sn; }
                if (t2 >= rem && t3 < rem) { sh_T = prefix | ((unsigned)(4 * lane + 2) << sh); sh_rem = rem - t3; }
                if (t1 >= rem && t2 < rem) { sh_T = prefix | ((unsigned)(4 * lane + 1) << sh); sh_rem = rem - t2; }
                if (t0 >= rem && t1 < rem) { sh_T = prefix | ((unsigned)(4 * lane + 0) << sh); sh_rem = rem - t1; }
            }
            __syncthreads();
            prefix = sh_T;
            maskHi |= 0xffu << sh;
            remaining = sh_rem;
        }

        const unsigned T = prefix;
        const unsigned eqTake = remaining;

        unsigned gtm = 0, eqm = 0;
#pragma unroll
        for (int c = 0; c < NCHUNK; ++c) {
            if (c < nk) {
                if (key[c] > T)       gtm |= 1u << c;
                else if (key[c] == T) eqm |= 1u << c;
            }
        }
#pragma unroll
        for (int c = 0; c < NCHUNK; ++c) {
            unsigned long long bal = __ballot((eqm >> c) & 1u);
            if (lane == 0) waveEq[c][wv] = (unsigned)__popcll(bal);
        }
        __syncthreads();
        if (tid < 64) {
            unsigned s = 0;
            for (int p = lane; p < NCHUNK * 8; p += 64) s += waveEq[p >> 3][p & 7];
#pragma unroll
            for (int off = 32; off > 0; off >>= 1) s += __shfl_down(s, off, 64);
            if (lane == 0) sh_totEq = s;
        }
        __syncthreads();
        const bool fast = (sh_totEq == eqTake);
        if (!fast) {
            if (tid == 0) {
                unsigned run = 0;
                for (int c = 0; c < NCHUNK; ++c)
                    for (int w = 0; w < 8; ++w) { waveEqPre[c][w] = run; run += waveEq[c][w]; }
            }
            __syncthreads();
        }
#pragma unroll
        for (int c = 0; c < NCHUNK; ++c) {
            bool eq = (eqm >> c) & 1u;
            bool take;
            if (fast) {
                take = (((gtm >> c) & 1u) != 0u) || eq;
            } else {
                unsigned long long balEq = __ballot(eq);
                unsigned rank = waveEqPre[c][wv] + (unsigned)__popcll(balEq & ((1ull << lane) - 1ull));
                take = (((gtm >> c) & 1u) != 0u) || (eq && rank < eqTake);
            }
            unsigned long long balT = __ballot(take);
            int w0 = c * 16 + wv * 2;          // chunk c covers words [c*16, c*16+16)
            if (w0 < MASK_WORDS && lane == 0) {
                maskbits_g[w0]     = (unsigned)balT;
                maskbits_g[w0 + 1] = (unsigned)(balT >> 32);
            }
        }
        __syncthreads();
        if (tid == 0) {
            __threadfence();   // make maskbits visible device-wide, then release flag
            __hip_atomic_store(flag_g, 1u, __ATOMIC_RELEASE, __HIP_MEMORY_SCOPE_AGENT);
        }
        return;
    }

    // ===================== workers 1..256 =====================
    const int g = bid - 1;                           // 0..255; W rows [g*16,(g+1)*16)
    const float4* wp = (const float4*)(W + (size_t)g * (ROWS_PER_BLOCK * IN_F));
    const bool doRecall = (g < NCACHE);

    if (doRecall) {
        // build rowbits for cached row g during the select shadow (mask-independent)
        for (int w = tid; w < MASK_WORDS; w += NTHR) rowbits[w] = 0;
        __syncthreads();
        const int4* ci4 = (const int4*)(cached + (size_t)g * TOPK_K);
        for (int t = tid; t < TOPK_K / 4; t += NTHR) {
            int4 v = ci4[t];
            atomicOr(&rowbits[v.x >> 5], 1u << (v.x & 31));
            atomicOr(&rowbits[v.y >> 5], 1u << (v.y & 31));
            atomicOr(&rowbits[v.z >> 5], 1u << (v.z & 31));
            atomicOr(&rowbits[v.w >> 5], 1u << (v.w & 31));
        }
        __syncthreads();
    }

    // prefetch own W slice into L2/L3 while select runs (stop on flag; hint only)
    {
        const int NCH = (ROWS_PER_BLOCK * IN_F / 4) / (2 * NTHR);   // 43 chunks of 16KB
        for (int c = 0; c < NCH; ++c) {
            if (c >= 1 && __hip_atomic_load(flag_g, __ATOMIC_RELAXED, __HIP_MEMORY_SCOPE_AGENT) != 0u)
                break;
            float4 a = wp[c * 2 * NTHR + tid];
            float4 b = wp[c * 2 * NTHR + NTHR + tid];
            asm volatile("" :: "v"(a.x), "v"(a.y), "v"(a.z), "v"(a.w));
            asm volatile("" :: "v"(b.x), "v"(b.y), "v"(b.z), "v"(b.w));
        }
    }

    // wait for mask
    if (tid == 0) {
        while (__hip_atomic_load(flag_g, __ATOMIC_ACQUIRE, __HIP_MEMORY_SCOPE_AGENT) == 0u)
            __builtin_amdgcn_s_sleep(8);
    }
    __syncthreads();

    if (doRecall) {   // intersect -> score for cached row g
        unsigned cnt = 0;
        for (int w = tid; w < MASK_WORDS; w += NTHR) cnt += __popc(rowbits[w] & maskbits_g[w]);
        for (int off = 32; off > 0; off >>= 1) cnt += __shfl_down(cnt, off, 64);
        if (lane == 0) wsum[wv] = cnt;
        __syncthreads();
        if (tid == 0) {
            unsigned tot = 0;
#pragma unroll
            for (int w = 0; w < 8; ++w) tot += wsum[w];
            atomicMax(score_g, (tot << 6) | (unsigned)(63 - g));
            __hip_atomic_fetch_add(done_g, 1u, __ATOMIC_RELEASE, __HIP_MEMORY_SCOPE_AGENT);
        }
    }

    // xs = mask .* x (speculative topk path)
    {
        const float4* x4 = (const float4*)x;
        for (int j = tid; j < IN_F / 4; j += NTHR) {
            float4 xv = x4[j];
            int base = j * 4;
            unsigned wbits = maskbits_g[base >> 5];
            int sh = base & 31;
            xs[base + 0] = xv.x * (float)((wbits >> (sh + 0)) & 1u);
            xs[base + 1] = xv.y * (float)((wbits >> (sh + 1)) & 1u);
            xs[base + 2] = xv.z * (float)((wbits >> (sh + 2)) & 1u);
            xs[base + 3] = xv.w * (float)((wbits >> (sh + 3)) & 1u);
        }
    }
    __syncthreads();

    const int row0 = g * ROWS_PER_BLOCK + wv * 2;
    const int row1 = row0 + 1;
    const float4* w0p = (const float4*)(W + (size_t)row0 * IN_F);
    const float4* w1p = (const float4*)(W + (size_t)row1 * IN_F);
    const float4* xs4 = (const float4*)xs;

    float acc0 = 0.f, acc1 = 0.f;
#pragma unroll 4
    for (int j = lane; j < IN_F / 4; j += 64) {   // exactly 43 iters/lane
        float4 xv = xs4[j];
        float4 a  = w0p[j];
        float4 b  = w1p[j];
        acc0 += xv.x * a.x + xv.y * a.y + xv.z * a.z + xv.w * a.w;
        acc1 += xv.x * b.x + xv.y * b.y + xv.z * b.z + xv.w * b.w;
    }
    for (int off = 32; off > 0; off >>= 1) {
        acc0 += __shfl_down(acc0, off, 64);
        acc1 += __shfl_down(acc1, off, 64);
    }

    // wait for all 64 recall publishers (finished long ago in practice)
    if (tid == 0) {
        while (__hip_atomic_load(done_g, __ATOMIC_ACQUIRE, __HIP_MEMORY_SCOPE_AGENT) < NCACHE)
            __builtin_amdgcn_s_sleep(2);
    }
    __syncthreads();

    unsigned score = *score_g;
    bool useCache = ((float)(score >> 6) / (float)TOPK_K) >= 0.9f;
    if (!useCache) {
        if (lane == 0) {
            out[row0] = acc0 + bias[row0];
            out[row1] = acc1 + bias[row1];
        }
    } else {
        // rare exact path: xs[i] = multiplicity(i in best row) * x[i]
        int best = 63 - (int)(score & 63u);
        __syncthreads();
        for (int i = tid; i < IN_F; i += NTHR) xs[i] = 0.f;
        __syncthreads();
        const int* ci = cached + (size_t)best * TOPK_K;
        for (int t = tid; t < TOPK_K; t += NTHR) {
            int idx = ci[t];
            atomicAdd(&xs[idx], x[idx]);   // duplicates accumulate -> count*x
        }
        __syncthreads();
        float a0 = 0.f, a1 = 0.f;
#pragma unroll 4
        for (int j = lane; j < IN_F / 4; j += 64) {
            float4 xv = xs4[j];
            float4 a  = w0p[j];
            float4 b  = w1p[j];
            a0 += xv.x * a.x + xv.y * a.y + xv.z * a.z + xv.w * a.w;
            a1 += xv.x * b.x + xv.y * b.y + xv.z * b.z + xv.w * b.w;
        }
        for (int off = 32; off > 0; off >>= 1) {
            a0 += __shfl_down(a0, off, 64);
            a1 += __shfl_down(a1, off, 64);
        }
        if (lane == 0) {
            out[row0] = a0 + bias[row0];
            out[row1] = a1 + bias[row1];
        }
    }
}

extern "C" void kernel_launch(void* const* d_in, const int* in_sizes, int n_in,
                              void* d_out, int out_size, void* d_ws, size_t ws_size,
                              hipStream_t stream) {
    const float* x      = (const float*)d_in[0];
    const float* W      = (const float*)d_in[1];
    const float* bias   = (const float*)d_in[2];
    const int*   cached = (const int*)d_in[3];
    float* out = (float*)d_out;

    char* ws = (char*)d_ws;
    unsigned* maskbits = (unsigned*)(ws + 0);
    unsigned* score    = (unsigned*)(ws + 1472);
    unsigned* flag     = (unsigned*)(ws + 1476);
    unsigned* done     = (unsigned*)(ws + 1480);

    hipMemsetAsync(ws + 1472, 0, 12, stream);   // score, flag, done
    k_all<<<NBLK, NTHR, 0, stream>>>(x, W, bias, cached, out,
                                     maskbits, score, flag, done);
    // MEASUREMENT: second idempotent run. dur_us(R9) - dur_us(R8) isolates
    // T(GEMV | warm L3, flag pre-set, no prefetch/sync exposure).
    k_all<<<NBLK, NTHR, 0, stream>>>(x, W, bias, cached, out,
                                     maskbits, score, flag, done);
}

// Round 10
// 264.343 us; speedup vs baseline: 1.1124x; 1.1124x over previous
//
#include <hip/hip_runtime.h>
#include <stdint.h>

#define IN_F   11008
#define OUT_F  4096
#define TOPK_K 5504
#define NCACHE 64
#define MASK_WORDS 344   // 11008 / 32
#define NTHR   512
#define NCHUNK 22        // ceil(11008 / 512) select keys per thread
#define ROWS_PER_BLOCK 16
#define NWORK  (OUT_F / ROWS_PER_BLOCK)   // 256 worker blocks, 1 per CU
#define NBLK   (1 + NWORK)                // 257

// ws layout (bytes):
//   [0    , 1376) : topk mask bits (344 u32)              (exact; recall + slow paths)
//   [1472 , 1476) : packed score u32, atomicMax of (inter<<6)|(63-row)
//   [1476 , 1480) : T-flag: bit0 = T ready, bit1 = fast (all ties taken)
//   [1480 , 1484) : recall-done counter
//   [1484 , 1488) : mask-ready flag
//   [1488 , 1492) : T (threshold key), written before T-flag release
// (score/Tflag/done/maskflag zeroed by hipMemsetAsync before launch)

__device__ __forceinline__ unsigned absbits(float v) {
    return __float_as_uint(v) & 0x7fffffffu;
}

// ---------------------------------------------------------------------------
// Single fused kernel, 257 blocks x 512 threads.
//   block 0   : radix-select; release {T, fast} right after the passes (before
//               mask build); then build+publish exact maskbits, release maskflag.
//   workers   : prefetch own 16-row W slice (8 loads / 1 sink / 1 flag check
//               per 64KB round) -> spin T-flag -> [recall blocks: spin maskflag,
//               intersect, publish score] -> GEMV with ON-THE-FLY x masking
//               (key >= T; exact when fast) -> spin done -> epilogue: if
//               useCache or !fast, rebuild xs exactly (counts / maskbits) and
//               redo GEMV (rare); else write out.
// Dependency DAG acyclic; all 257 blocks co-resident (LDS ~56KB -> 2/CU).
// ---------------------------------------------------------------------------
__global__ __launch_bounds__(NTHR, 4) void k_all(const float* __restrict__ x,
                                                 const float* __restrict__ W,
                                                 const float* __restrict__ bias,
                                                 const int* __restrict__ cached,
                                                 float* __restrict__ out,
                                                 unsigned* __restrict__ maskbits_g,
                                                 unsigned* __restrict__ score_g,
                                                 unsigned* __restrict__ flag_g,
                                                 unsigned* __restrict__ done_g,
                                                 unsigned* __restrict__ maskflag_g,
                                                 unsigned* __restrict__ Tval_g) {
    __shared__ unsigned hist[8][256];    // select: per-wave private hists (8KB)
    __shared__ unsigned csum[256];
    __shared__ unsigned sh_T, sh_rem, sh_totEq;
    __shared__ unsigned waveEq[NCHUNK][8];
    __shared__ unsigned waveEqPre[NCHUNK][8];
    __shared__ unsigned rowbits[MASK_WORDS];   // recall
    __shared__ unsigned wsum[8];
    __shared__ unsigned sh_flagv, sh_Tv;
    __shared__ __align__(16) float xs[IN_F];   // select x-stage / rare-path xs (44KB)

    const int tid  = threadIdx.x;
    const int wv   = tid >> 6;
    const int lane = tid & 63;
    const int bid  = blockIdx.x;

    // ===================== block 0: radix-select =====================
    if (bid == 0) {
        {   // batched x ingest: 6 independent float4 loads -> LDS -> strided re-read
            float4* xs4w = (float4*)xs;
#pragma unroll
            for (int k = 0; k < 6; ++k) {
                int j = k * NTHR + tid;
                if (j < IN_F / 4) xs4w[j] = ((const float4*)x)[j];
            }
        }
        __syncthreads();

        const int nk = (tid < 256) ? NCHUNK : NCHUNK - 1;   // 11008 = 21*512 + 256

        unsigned key[NCHUNK];
#pragma unroll
        for (int c = 0; c < NCHUNK; ++c) {
            key[c] = 0u;
            if (c < nk) key[c] = absbits(xs[c * NTHR + tid]);
        }
        __syncthreads();

        unsigned prefix = 0, maskHi = 0, remaining = TOPK_K;

        for (int pass = 3; pass >= 0; --pass) {
            const int sh = pass * 8;
            for (int b = tid; b < 8 * 256; b += NTHR) ((unsigned*)hist)[b] = 0;
            __syncthreads();
#pragma unroll
            for (int c = 0; c < NCHUNK; ++c) {
                if (c < nk && (key[c] & maskHi) == prefix)
                    atomicAdd(&hist[wv][(key[c] >> sh) & 255], 1u);
            }
            __syncthreads();
            if (tid < 256) {          // merge 8 hists, conflict-free
                unsigned s = 0;
#pragma unroll
                for (int w = 0; w < 8; ++w) s += hist[w][tid];
                csum[tid] = s;
            }
            __syncthreads();
            if (wv == 0) {
                // lane l owns buckets [4l,4l+4); inclusive suffix-scan across lanes
                unsigned c0 = csum[4 * lane + 0], c1 = csum[4 * lane + 1];
                unsigned c2 = csum[4 * lane + 2], c3 = csum[4 * lane + 3];
                unsigned S = c0 + c1 + c2 + c3;
#pragma unroll
                for (int off = 1; off < 64; off <<= 1) {
                    unsigned v = __shfl_down(S, off, 64);
                    if (lane + off < 64) S += v;
                }
                unsigned Sn = __shfl_down(S, 1, 64);
                if (lane == 63) Sn = 0;
                unsigned t3 = Sn + c3;
                unsigned t2 = t3 + c2;
                unsigned t1 = t2 + c1;
                unsigned t0 = t1 + c0;
                unsigned rem = remaining;
                if (t3 >= rem && Sn < rem) { sh_T = prefix | ((unsigned)(4 * lane + 3) << sh); sh_rem = rem - Sn; }
                if (t2 >= rem && t3 < rem) { sh_T = prefix | ((unsigned)(4 * lane + 2) << sh); sh_rem = rem - t3; }
                if (t1 >= rem && t2 < rem) { sh_T = prefix | ((unsigned)(4 * lane + 1) << sh); sh_rem = rem - t2; }
                if (t0 >= rem && t1 < rem) { sh_T = prefix | ((unsigned)(4 * lane + 0) << sh); sh_rem = rem - t1; }
            }
            __syncthreads();
            prefix = sh_T;
            maskHi |= 0xffu << sh;
            remaining = sh_rem;
        }

        const unsigned T = prefix;
        const unsigned eqTake = remaining;

        unsigned gtm = 0, eqm = 0;
#pragma unroll
        for (int c = 0; c < NCHUNK; ++c) {
            if (c < nk) {
                if (key[c] > T)       gtm |= 1u << c;
                else if (key[c] == T) eqm |= 1u << c;
            }
        }
#pragma unroll
        for (int c = 0; c < NCHUNK; ++c) {
            unsigned long long bal = __ballot((eqm >> c) & 1u);
            if (lane == 0) waveEq[c][wv] = (unsigned)__popcll(bal);
        }
        __syncthreads();
        if (tid < 64) {
            unsigned s = 0;
            for (int p = lane; p < NCHUNK * 8; p += 64) s += waveEq[p >> 3][p & 7];
#pragma unroll
            for (int off = 32; off > 0; off >>= 1) s += __shfl_down(s, off, 64);
            if (lane == 0) sh_totEq = s;
        }
        __syncthreads();
        const bool fast = (sh_totEq == eqTake);

        // EARLY RELEASE: workers only need T + fast verdict to start the GEMV.
        if (tid == 0) {
            *Tval_g = T;
            __threadfence();
            __hip_atomic_store(flag_g, 1u | (fast ? 2u : 0u),
                               __ATOMIC_RELEASE, __HIP_MEMORY_SCOPE_AGENT);
        }

        if (!fast) {
            if (tid == 0) {
                unsigned run = 0;
                for (int c = 0; c < NCHUNK; ++c)
                    for (int w = 0; w < 8; ++w) { waveEqPre[c][w] = run; run += waveEq[c][w]; }
            }
            __syncthreads();
        }
#pragma unroll
        for (int c = 0; c < NCHUNK; ++c) {
            bool eq = (eqm >> c) & 1u;
            bool take;
            if (fast) {
                take = (((gtm >> c) & 1u) != 0u) || eq;
            } else {
                unsigned long long balEq = __ballot(eq);
                unsigned rank = waveEqPre[c][wv] + (unsigned)__popcll(balEq & ((1ull << lane) - 1ull));
                take = (((gtm >> c) & 1u) != 0u) || (eq && rank < eqTake);
            }
            unsigned long long balT = __ballot(take);
            int w0 = c * 16 + wv * 2;          // chunk c covers words [c*16, c*16+16)
            if (w0 < MASK_WORDS && lane == 0) {
                maskbits_g[w0]     = (unsigned)balT;
                maskbits_g[w0 + 1] = (unsigned)(balT >> 32);
            }
        }
        __syncthreads();
        if (tid == 0) {
            __threadfence();
            __hip_atomic_store(maskflag_g, 1u, __ATOMIC_RELEASE, __HIP_MEMORY_SCOPE_AGENT);
        }
        return;
    }

    // ===================== workers 1..256 =====================
    const int g = bid - 1;                           // 0..255; W rows [g*16,(g+1)*16)
    const float4* wp = (const float4*)(W + (size_t)g * (ROWS_PER_BLOCK * IN_F));
    const bool doRecall = (g < NCACHE);

    if (doRecall) {
        // build rowbits for cached row g during the select shadow (mask-independent)
        for (int w = tid; w < MASK_WORDS; w += NTHR) rowbits[w] = 0;
        __syncthreads();
        const int4* ci4 = (const int4*)(cached + (size_t)g * TOPK_K);
        for (int t = tid; t < TOPK_K / 4; t += NTHR) {
            int4 v = ci4[t];
            atomicOr(&rowbits[v.x >> 5], 1u << (v.x & 31));
            atomicOr(&rowbits[v.y >> 5], 1u << (v.y & 31));
            atomicOr(&rowbits[v.z >> 5], 1u << (v.z & 31));
            atomicOr(&rowbits[v.w >> 5], 1u << (v.w & 31));
        }
        __syncthreads();
    }

    // prefetch own W slice into L2/L3 while select runs (hint only).
    // 8 loads -> 8 sinks -> 1 flag check per 64KB round: deep MLP, 4x fewer
    // contended flag reads than per-16KB checking.
    {
        bool stop = false;
        for (int r = 0; r < 10; ++r) {   // rounds cover float4s [r*4096,(r+1)*4096)
            if (r > 0 && __hip_atomic_load(flag_g, __ATOMIC_RELAXED, __HIP_MEMORY_SCOPE_AGENT) != 0u) {
                stop = true; break;
            }
            const int base = r * 4096;
            float4 a0 = wp[base +    0 + tid];
            float4 a1 = wp[base +  512 + tid];
            float4 a2 = wp[base + 1024 + tid];
            float4 a3 = wp[base + 1536 + tid];
            float4 a4 = wp[base + 2048 + tid];
            float4 a5 = wp[base + 2560 + tid];
            float4 a6 = wp[base + 3072 + tid];
            float4 a7 = wp[base + 3584 + tid];
            asm volatile("" :: "v"(a0.x), "v"(a0.y), "v"(a0.z), "v"(a0.w));
            asm volatile("" :: "v"(a1.x), "v"(a1.y), "v"(a1.z), "v"(a1.w));
            asm volatile("" :: "v"(a2.x), "v"(a2.y), "v"(a2.z), "v"(a2.w));
            asm volatile("" :: "v"(a3.x), "v"(a3.y), "v"(a3.z), "v"(a3.w));
            asm volatile("" :: "v"(a4.x), "v"(a4.y), "v"(a4.z), "v"(a4.w));
            asm volatile("" :: "v"(a5.x), "v"(a5.y), "v"(a5.z), "v"(a5.w));
            asm volatile("" :: "v"(a6.x), "v"(a6.y), "v"(a6.z), "v"(a6.w));
            asm volatile("" :: "v"(a7.x), "v"(a7.y), "v"(a7.z), "v"(a7.w));
        }
        if (!stop && __hip_atomic_load(flag_g, __ATOMIC_RELAXED, __HIP_MEMORY_SCOPE_AGENT) == 0u) {
            const int base = 40960;   // tail float4s [40960, 44032)
            float4 a0 = wp[base +    0 + tid];
            float4 a1 = wp[base +  512 + tid];
            float4 a2 = wp[base + 1024 + tid];
            float4 a3 = wp[base + 1536 + tid];
            float4 a4 = wp[base + 2048 + tid];
            float4 a5 = wp[base + 2560 + tid];
            asm volatile("" :: "v"(a0.x), "v"(a0.y), "v"(a0.z), "v"(a0.w));
            asm volatile("" :: "v"(a1.x), "v"(a1.y), "v"(a1.z), "v"(a1.w));
            asm volatile("" :: "v"(a2.x), "v"(a2.y), "v"(a2.z), "v"(a2.w));
            asm volatile("" :: "v"(a3.x), "v"(a3.y), "v"(a3.z), "v"(a3.w));
            asm volatile("" :: "v"(a4.x), "v"(a4.y), "v"(a4.z), "v"(a4.w));
            asm volatile("" :: "v"(a5.x), "v"(a5.y), "v"(a5.z), "v"(a5.w));
        }
    }

    // wait for T
    if (tid == 0) {
        unsigned f;
        while ((f = __hip_atomic_load(flag_g, __ATOMIC_ACQUIRE, __HIP_MEMORY_SCOPE_AGENT)) == 0u)
            __builtin_amdgcn_s_sleep(8);
        sh_flagv = f;
        sh_Tv = *Tval_g;
    }
    __syncthreads();
    const bool fastSel = (sh_flagv & 2u) != 0u;
    const unsigned Tv  = sh_Tv;

    if (doRecall) {   // exact intersect needs the full mask
        if (tid == 0) {
            while (__hip_atomic_load(maskflag_g, __ATOMIC_ACQUIRE, __HIP_MEMORY_SCOPE_AGENT) == 0u)
                __builtin_amdgcn_s_sleep(4);
        }
        __syncthreads();
        unsigned cnt = 0;
        for (int w = tid; w < MASK_WORDS; w += NTHR) cnt += __popc(rowbits[w] & maskbits_g[w]);
        for (int off = 32; off > 0; off >>= 1) cnt += __shfl_down(cnt, off, 64);
        if (lane == 0) wsum[wv] = cnt;
        __syncthreads();
        if (tid == 0) {
            unsigned tot = 0;
#pragma unroll
            for (int w = 0; w < 8; ++w) tot += wsum[w];
            atomicMax(score_g, (tot << 6) | (unsigned)(63 - g));
            __hip_atomic_fetch_add(done_g, 1u, __ATOMIC_RELEASE, __HIP_MEMORY_SCOPE_AGENT);
        }
    }

    // speculative GEMV: mask x on the fly via key >= T (exact when fastSel).
    // No xs build, no mask read, no extra barrier on the critical path.
    const int row0 = g * ROWS_PER_BLOCK + wv * 2;
    const int row1 = row0 + 1;
    const float4* w0p = (const float4*)(W + (size_t)row0 * IN_F);
    const float4* w1p = (const float4*)(W + (size_t)row1 * IN_F);
    const float4* x4g = (const float4*)x;

    float acc0 = 0.f, acc1 = 0.f;
#pragma unroll 4
    for (int j = lane; j < IN_F / 4; j += 64) {   // exactly 43 iters/lane
        float4 xv = x4g[j];
        xv.x = (absbits(xv.x) >= Tv) ? xv.x : 0.f;
        xv.y = (absbits(xv.y) >= Tv) ? xv.y : 0.f;
        xv.z = (absbits(xv.z) >= Tv) ? xv.z : 0.f;
        xv.w = (absbits(xv.w) >= Tv) ? xv.w : 0.f;
        float4 a  = w0p[j];
        float4 b  = w1p[j];
        acc0 += xv.x * a.x + xv.y * a.y + xv.z * a.z + xv.w * a.w;
        acc1 += xv.x * b.x + xv.y * b.y + xv.z * b.z + xv.w * b.w;
    }
    for (int off = 32; off > 0; off >>= 1) {
        acc0 += __shfl_down(acc0, off, 64);
        acc1 += __shfl_down(acc1, off, 64);
    }

    // wait for all 64 recall publishers
    if (tid == 0) {
        while (__hip_atomic_load(done_g, __ATOMIC_ACQUIRE, __HIP_MEMORY_SCOPE_AGENT) < NCACHE)
            __builtin_amdgcn_s_sleep(2);
    }
    __syncthreads();

    unsigned score = *score_g;
    bool useCache = ((float)(score >> 6) / (float)TOPK_K) >= 0.9f;
    bool redo = useCache || !fastSel;
    if (!redo) {
        if (lane == 0) {
            out[row0] = acc0 + bias[row0];
            out[row1] = acc1 + bias[row1];
        }
    } else {
        // rare exact paths: rebuild xs, redo GEMV.
        const float4* xs4 = (const float4*)xs;
        __syncthreads();
        if (useCache) {
            // xs[i] = multiplicity(i in best row) * x[i]
            int best = 63 - (int)(score & 63u);
            for (int i = tid; i < IN_F; i += NTHR) xs[i] = 0.f;
            __syncthreads();
            const int* ci = cached + (size_t)best * TOPK_K;
            for (int t = tid; t < TOPK_K; t += NTHR) {
                int idx = ci[t];
                atomicAdd(&xs[idx], x[idx]);   // duplicates accumulate -> count*x
            }
            __syncthreads();
        } else {
            // slow tie path: exact mask multiply from maskbits
            if (tid == 0) {
                while (__hip_atomic_load(maskflag_g, __ATOMIC_ACQUIRE, __HIP_MEMORY_SCOPE_AGENT) == 0u)
                    __builtin_amdgcn_s_sleep(4);
            }
            __syncthreads();
            for (int j = tid; j < IN_F / 4; j += NTHR) {
                float4 xv = x4g[j];
                int base = j * 4;
                unsigned wbits = maskbits_g[base >> 5];
                int sh = base & 31;
                xs[base + 0] = xv.x * (float)((wbits >> (sh + 0)) & 1u);
                xs[base + 1] = xv.y * (float)((wbits >> (sh + 1)) & 1u);
                xs[base + 2] = xv.z * (float)((wbits >> (sh + 2)) & 1u);
                xs[base + 3] = xv.w * (float)((wbits >> (sh + 3)) & 1u);
            }
            __syncthreads();
        }
        float a0 = 0.f, a1 = 0.f;
#pragma unroll 4
        for (int j = lane; j < IN_F / 4; j += 64) {
            float4 xv = xs4[j];
            float4 a  = w0p[j];
            float4 b  = w1p[j];
            a0 += xv.x * a.x + xv.y * a.y + xv.z * a.z + xv.w * a.w;
            a1 += xv.x * b.x + xv.y * b.y + xv.z * b.z + xv.w * b.w;
        }
        for (int off = 32; off > 0; off >>= 1) {
            a0 += __shfl_down(a0, off, 64);
            a1 += __shfl_down(a1, off, 64);
        }
        if (lane == 0) {
            out[row0] = a0 + bias[row0];
            out[row1] = a1 + bias[row1];
        }
    }
}

extern "C" void kernel_launch(void* const* d_in, const int* in_sizes, int n_in,
                              void* d_out, int out_size, void* d_ws, size_t ws_size,
                              hipStream_t stream) {
    const float* x      = (const float*)d_in[0];
    const float* W      = (const float*)d_in[1];
    const float* bias   = (const float*)d_in[2];
    const int*   cached = (const int*)d_in[3];
    float* out = (float*)d_out;

    char* ws = (char*)d_ws;
    unsigned* maskbits = (unsigned*)(ws + 0);
    unsigned* score    = (unsigned*)(ws + 1472);
    unsigned* flag     = (unsigned*)(ws + 1476);
    unsigned* done     = (unsigned*)(ws + 1480);
    unsigned* maskflag = (unsigned*)(ws + 1484);
    unsigned* Tval     = (unsigned*)(ws + 1488);

    hipMemsetAsync(ws + 1472, 0, 16, stream);   // score, flag, done, maskflag
    k_all<<<NBLK, NTHR, 0, stream>>>(x, W, bias, cached, out,
                                     maskbits, score, flag, done, maskflag, Tval);
}